// Round 1
// baseline (186.314 us; speedup 1.0000x reference)
//
#include <hip/hip_runtime.h>
#include <math.h>

#define NHEADS 8
#define DHEAD 64
#define NDIM 512
#define NFREQ 32
#define POSD 130           // 2*(32*2+1)
#define NB 2
#define NL 272
#define NLS 256
#define NROWS (NB*NL)      // 544
#define ATTN_SCALE 0.125f
#define PHYS_SCALE 51.5f
#define PI_F 3.14159265358979323846f

// ---------------------------------------------------------------------------
// K1: qkv = x @ [Wq | Wk[:512] | Wv[:512]]   (M=544, N=1536, K=512, fp32)
// ---------------------------------------------------------------------------
__global__ __launch_bounds__(256) void qkv_gemm_k(
    const float* __restrict__ x,
    const float* __restrict__ Wq, const float* __restrict__ Wk,
    const float* __restrict__ Wv,
    float* __restrict__ qkv)   // [3][544][512] : q, k_base, v_base
{
  __shared__ float As[16][68];   // [k][m], pad 4 keeps float4 alignment, no conflicts
  __shared__ float Bs[16][64];   // [k][n]
  const int t  = threadIdx.x;
  const int m0 = blockIdx.x * 64;
  const int ng = blockIdx.y * 64;          // 0..1535
  const int region = ng >> 9;              // 0:q 1:k 2:v  (64 | 512 so uniform)
  const int n0 = ng & 511;
  const float* W = (region == 0) ? Wq : (region == 1) ? Wk : Wv;
  float* out = qkv + (size_t)region * (NROWS * NDIM);

  const int tx = t & 15, ty = t >> 4;
  const int arow = t >> 2, akq = (t & 3) * 4;
  const int brow = t >> 4, bcol = (t & 15) * 4;

  float acc[4][4];
#pragma unroll
  for (int i = 0; i < 4; ++i)
#pragma unroll
    for (int j = 0; j < 4; ++j) acc[i][j] = 0.f;

  for (int k0 = 0; k0 < 512; k0 += 16) {
    float4 av = make_float4(0.f, 0.f, 0.f, 0.f);
    if (m0 + arow < NROWS)
      av = *(const float4*)&x[(size_t)(m0 + arow) * NDIM + k0 + akq];
    As[akq + 0][arow] = av.x; As[akq + 1][arow] = av.y;
    As[akq + 2][arow] = av.z; As[akq + 3][arow] = av.w;
    *(float4*)&Bs[brow][bcol] =
        *(const float4*)&W[(size_t)(k0 + brow) * NDIM + n0 + bcol];
    __syncthreads();
#pragma unroll
    for (int kk = 0; kk < 16; ++kk) {
      float4 a = *(const float4*)&As[kk][ty * 4];
      float4 b = *(const float4*)&Bs[kk][tx * 4];
      float aa[4] = {a.x, a.y, a.z, a.w};
      float bb[4] = {b.x, b.y, b.z, b.w};
#pragma unroll
      for (int i = 0; i < 4; ++i)
#pragma unroll
        for (int j = 0; j < 4; ++j) acc[i][j] = fmaf(aa[i], bb[j], acc[i][j]);
    }
    __syncthreads();
  }
#pragma unroll
  for (int i = 0; i < 4; ++i) {
    int row = m0 + ty * 4 + i;
    if (row < NROWS)
      *(float4*)&out[(size_t)row * NDIM + n0 + tx * 4] =
          make_float4(acc[i][0], acc[i][1], acc[i][2], acc[i][3]);
  }
}

// ---------------------------------------------------------------------------
// K3: out = attn_out @ Wo + bo   (M=544, N=512, K=512)
// ---------------------------------------------------------------------------
__global__ __launch_bounds__(256) void out_gemm_k(
    const float* __restrict__ A, const float* __restrict__ Wo,
    const float* __restrict__ bo, float* __restrict__ out)
{
  __shared__ float As[16][68];
  __shared__ float Bs[16][64];
  const int t  = threadIdx.x;
  const int m0 = blockIdx.x * 64;
  const int n0 = blockIdx.y * 64;

  const int tx = t & 15, ty = t >> 4;
  const int arow = t >> 2, akq = (t & 3) * 4;
  const int brow = t >> 4, bcol = (t & 15) * 4;

  float acc[4][4];
#pragma unroll
  for (int i = 0; i < 4; ++i)
#pragma unroll
    for (int j = 0; j < 4; ++j) acc[i][j] = 0.f;

  for (int k0 = 0; k0 < 512; k0 += 16) {
    float4 av = make_float4(0.f, 0.f, 0.f, 0.f);
    if (m0 + arow < NROWS)
      av = *(const float4*)&A[(size_t)(m0 + arow) * NDIM + k0 + akq];
    As[akq + 0][arow] = av.x; As[akq + 1][arow] = av.y;
    As[akq + 2][arow] = av.z; As[akq + 3][arow] = av.w;
    *(float4*)&Bs[brow][bcol] =
        *(const float4*)&Wo[(size_t)(k0 + brow) * NDIM + n0 + bcol];
    __syncthreads();
#pragma unroll
    for (int kk = 0; kk < 16; ++kk) {
      float4 a = *(const float4*)&As[kk][ty * 4];
      float4 b = *(const float4*)&Bs[kk][tx * 4];
      float aa[4] = {a.x, a.y, a.z, a.w};
      float bb[4] = {b.x, b.y, b.z, b.w};
#pragma unroll
      for (int i = 0; i < 4; ++i)
#pragma unroll
        for (int j = 0; j < 4; ++j) acc[i][j] = fmaf(aa[i], bb[j], acc[i][j]);
    }
    __syncthreads();
  }
  float4 bv = *(const float4*)&bo[n0 + tx * 4];
  float bb[4] = {bv.x, bv.y, bv.z, bv.w};
#pragma unroll
  for (int i = 0; i < 4; ++i) {
    int row = m0 + ty * 4 + i;
    if (row < NROWS)
      *(float4*)&out[(size_t)row * NDIM + n0 + tx * 4] =
          make_float4(acc[i][0] + bb[0], acc[i][1] + bb[1],
                      acc[i][2] + bb[2], acc[i][3] + bb[3]);
  }
}

// ---------------------------------------------------------------------------
// K2: fused attention. One block per (b, query i). 256 threads.
//   spatial i (<256): logits = scale*(q.k_base[j] + pe(i,j).u[h])  for j<256
//                              scale* q.k_base[j]                  for global keys
//   online softmax over 272 keys; PV accumulates v_base and w = sum_j p*pe;
//   epilogue adds w @ Wv_pe.
// ---------------------------------------------------------------------------
__global__ __launch_bounds__(256) void attn_k(
    const float* __restrict__ qb, const float* __restrict__ kb,
    const float* __restrict__ vb, const float* __restrict__ pos,
    const float* __restrict__ Wk, const float* __restrict__ Wv,
    const float* __restrict__ freqs, float* __restrict__ attn_out)
{
  __shared__ float q_s[NDIM];            // 512
  __shared__ float u_s[NHEADS][132];     // q @ Wk_pe^T (per head)
  __shared__ float pe_s[POSD][65];       // transposed pe tile [f][j], pad 65
  __shared__ float s_s[NHEADS][64];      // logits -> p
  __shared__ float w_s[NHEADS][132];     // gathered w for epilogue
  __shared__ float fr_s[NFREQ];
  __shared__ float m_s[NHEADS], l_s[NHEADS], fac_s[NHEADS];

  const int blk = blockIdx.x;
  const int b = blk / NL;
  const int i = blk - b * NL;
  const bool spatial = (i < NLS);
  const int t = threadIdx.x;
  const int row = b * NL + i;

  if (t < NFREQ) fr_s[t] = freqs[t];
  {
    float2 qv = *(const float2*)&qb[(size_t)row * NDIM + t * 2];
    q_s[t * 2] = qv.x; q_s[t * 2 + 1] = qv.y;
  }
  if (t < NHEADS) { m_s[t] = -1e30f; l_s[t] = 0.f; }
  __syncthreads();

  // u[h][f] = sum_d q[h*64+d] * Wk[512+f][h*64+d]   (spatial queries only)
  if (spatial) {
    for (int idx = t; idx < NHEADS * POSD; idx += 256) {
      int h = idx / POSD, f = idx - h * POSD;
      const float* wr = &Wk[(size_t)(512 + f) * NDIM + h * DHEAD];
      const float* qs = &q_s[h * DHEAD];
      float acc = 0.f;
#pragma unroll
      for (int d = 0; d < 64; d += 4) {
        float4 wv = *(const float4*)&wr[d];
        acc = fmaf(qs[d], wv.x, acc);
        acc = fmaf(qs[d + 1], wv.y, acc);
        acc = fmaf(qs[d + 2], wv.z, acc);
        acc = fmaf(qs[d + 3], wv.w, acc);
      }
      u_s[h][f] = acc;
    }
  }

  float px = 0.f, py = 0.f;
  if (spatial) {
    float2 pv = *(const float2*)&pos[(size_t)(b * NLS + i) * 2];
    px = pv.x; py = pv.y;
  }

  const int h_o = t >> 5;          // output head owned by this thread
  const int d0  = (t & 31) * 2;    // two dims owned
  float out0 = 0.f, out1 = 0.f;
  float w_own[5] = {0.f, 0.f, 0.f, 0.f, 0.f};

  for (int tile = 0; tile < 5; ++tile) {
    const int tn = (tile < 4) ? 64 : 16;
    const int key0 = tile * 64;                 // tile 4 -> keys 256..271
    const bool pe_act = spatial && (tile < 4);

    __syncthreads();   // protect pe_s / s_s reuse from previous tile

    // ---- phase A: polar encoding tile -> pe_s[f][j] (transposed) ----
    if (pe_act) {
      const int j = t >> 2;
      const int fq = (t & 3) * 8;
      float2 kp = *(const float2*)&pos[(size_t)(b * NLS + key0 + j) * 2];
      float dx = kp.x - px, dy = kp.y - py;
      float r = sqrtf(dx * dx + dy * dy + 1e-8f);
      float rc = r / (PHYS_SCALE + r);
      float thn = atan2f(dy, dx) * (1.0f / PI_F);
      if ((t & 3) == 0) { pe_s[64][j] = rc; pe_s[129][j] = thn; }
#pragma unroll
      for (int k = 0; k < 8; ++k) {
        int f = fq + k;
        float fr = fr_s[f];
        float s1, c1, s2, c2;
        __sincosf(rc * fr * PI_F, &s1, &c1);
        __sincosf(thn * fr * PI_F, &s2, &c2);
        pe_s[f][j] = s1;  pe_s[32 + f][j] = c1;
        pe_s[65 + f][j] = s2; pe_s[97 + f][j] = c2;
      }
    }
    __syncthreads();

    // ---- phase B: logits ----
#pragma unroll
    for (int rep = 0; rep < 2; ++rep) {
      int idx = t + rep * 256;
      int h = idx >> 6, j = idx & 63;
      if (j < tn) {
        const float* kr = &kb[(size_t)(b * NL + key0 + j) * NDIM + h * DHEAD];
        const float* qs = &q_s[h * DHEAD];
        float acc = 0.f;
#pragma unroll
        for (int d = 0; d < 64; d += 4) {
          float4 kv = *(const float4*)&kr[d];
          acc = fmaf(qs[d], kv.x, acc);
          acc = fmaf(qs[d + 1], kv.y, acc);
          acc = fmaf(qs[d + 2], kv.z, acc);
          acc = fmaf(qs[d + 3], kv.w, acc);
        }
        if (pe_act) {
          const float* uu = u_s[h];
#pragma unroll 2
          for (int f = 0; f < POSD; ++f)
            acc = fmaf(pe_s[f][j], uu[f], acc);
        }
        s_s[h][j] = acc * ATTN_SCALE;
      }
    }
    __syncthreads();

    // ---- phase C: online softmax update (32 threads per head) ----
    {
      const int hg = t >> 5, lane = t & 31;
      float v0 = (lane < tn) ? s_s[hg][lane] : -1e30f;
      float v1 = (lane + 32 < tn) ? s_s[hg][lane + 32] : -1e30f;
      float mx = fmaxf(v0, v1);
#pragma unroll
      for (int off = 16; off > 0; off >>= 1)
        mx = fmaxf(mx, __shfl_xor(mx, off, 32));
      float m_old = m_s[hg];
      float m_new = fmaxf(m_old, mx);
      float p0 = (lane < tn) ? __expf(v0 - m_new) : 0.f;
      float p1 = (lane + 32 < tn) ? __expf(v1 - m_new) : 0.f;
      if (lane < tn) s_s[hg][lane] = p0;
      if (lane + 32 < tn) s_s[hg][lane + 32] = p1;
      float sum = p0 + p1;
#pragma unroll
      for (int off = 16; off > 0; off >>= 1)
        sum += __shfl_xor(sum, off, 32);
      if (lane == 0) {
        float fac = __expf(m_old - m_new);
        m_s[hg] = m_new;
        l_s[hg] = l_s[hg] * fac + sum;
        fac_s[hg] = fac;
      }
    }
    __syncthreads();

    // ---- phase D: accumulate PV and w ----
    {
      float fac_o = fac_s[h_o];
      out0 *= fac_o; out1 *= fac_o;
      const float* vbase = &vb[(size_t)(b * NL + key0) * NDIM + h_o * DHEAD + d0];
      const float* pp = s_s[h_o];
      for (int j = 0; j < tn; ++j) {
        float p = pp[j];
        float2 vv = *(const float2*)&vbase[(size_t)j * NDIM];
        out0 = fmaf(p, vv.x, out0);
        out1 = fmaf(p, vv.y, out1);
      }
    }
    if (spatial) {
#pragma unroll
      for (int k = 0; k < 5; ++k) {
        int idx = t * 5 + k;
        if (idx < NHEADS * POSD) {
          int hw = idx / POSD, fw = idx - hw * POSD;
          float acc = w_own[k] * fac_s[hw];
          if (pe_act) {
            const float* per = pe_s[fw];
            const float* pp2 = s_s[hw];
#pragma unroll 4
            for (int j = 0; j < 64; ++j) acc = fmaf(pp2[j], per[j], acc);
          }
          w_own[k] = acc;
        }
      }
    }
  }

  // ---- epilogue ----
  __syncthreads();
  if (spatial) {
#pragma unroll
    for (int k = 0; k < 5; ++k) {
      int idx = t * 5 + k;
      if (idx < NHEADS * POSD) {
        int hw = idx / POSD, fw = idx - hw * POSD;
        w_s[hw][fw] = w_own[k];
      }
    }
  }
  __syncthreads();

  float invl = 1.0f / l_s[h_o];
  if (spatial) {
    const float* wvp = &Wv[(size_t)512 * NDIM + h_o * DHEAD + d0];
    const float* wsr = w_s[h_o];
#pragma unroll 2
    for (int f = 0; f < POSD; ++f) {
      float wq = wsr[f];
      float2 wv = *(const float2*)&wvp[(size_t)f * NDIM];
      out0 = fmaf(wq, wv.x, out0);
      out1 = fmaf(wq, wv.y, out1);
    }
  }
  attn_out[(size_t)row * NDIM + h_o * DHEAD + d0] = out0 * invl;
  attn_out[(size_t)row * NDIM + h_o * DHEAD + d0 + 1] = out1 * invl;
}

// ---------------------------------------------------------------------------
extern "C" void kernel_launch(void* const* d_in, const int* in_sizes, int n_in,
                              void* d_out, int out_size, void* d_ws, size_t ws_size,
                              hipStream_t stream)
{
  (void)in_sizes; (void)n_in; (void)out_size; (void)ws_size;
  const float* x     = (const float*)d_in[0];
  const float* pos   = (const float*)d_in[1];
  const float* Wq    = (const float*)d_in[2];
  const float* Wk    = (const float*)d_in[3];
  const float* Wv    = (const float*)d_in[4];
  const float* Wo    = (const float*)d_in[5];
  const float* bo    = (const float*)d_in[6];
  const float* freqs = (const float*)d_in[7];

  float* ws = (float*)d_ws;
  float* qkv = ws;                                   // [3][544][512]
  float* qb = qkv;
  float* kb = qkv + (size_t)NROWS * NDIM;
  float* vb = qkv + (size_t)2 * NROWS * NDIM;
  float* ao = qkv + (size_t)3 * NROWS * NDIM;        // attn_out [544][512]

  qkv_gemm_k<<<dim3((NROWS + 63) / 64, 24), 256, 0, stream>>>(x, Wq, Wk, Wv, qkv);
  attn_k<<<dim3(NB * NL), 256, 0, stream>>>(qb, kb, vb, pos, Wk, Wv, freqs, ao);
  out_gemm_k<<<dim3((NROWS + 63) / 64, 8), 256, 0, stream>>>(ao, Wo, bo, (float*)d_out);
}